// Round 13
// baseline (157.408 us; speedup 1.0000x reference)
//
#include <hip/hip_runtime.h>
#include <hip/hip_bf16.h>
#include <math.h>

#define N_IN 28
#define N_MID 256
#define N_OUT 28
#define SEQ 28
#define BATCH 4096
#define G3 768
#define ROWS 16
#define THREADS 1024            // 16 waves; wave w owns hidden cols [16w,16w+16)
#define NBLK (BATCH / ROWS)     // 256 blocks = 1/CU

typedef __attribute__((ext_vector_type(8))) short bf16x8;
typedef __attribute__((ext_vector_type(4))) float f32x4;

#define MFMA(a, b, c) __builtin_amdgcn_mfma_f32_16x16x32_bf16((a), (b), (c), 0, 0, 0)

__device__ __forceinline__ f32x4 splat4(float v) {
    f32x4 r;
    r[0] = v; r[1] = v; r[2] = v; r[3] = v;
    return r;
}

__device__ __forceinline__ short f2bf(float v) {          // RNE (prep kernel)
    __hip_bfloat16 b = __float2bfloat16(v);
    return *reinterpret_cast<short*>(&b);
}
__device__ __forceinline__ float bf2f(short s) {
    unsigned int u = ((unsigned int)(unsigned short)s) << 16;
    return __uint_as_float(u);
}
// HW packed f32->bf16 RNE: lo16 = bf16(a), hi16 = bf16(b)
__device__ __forceinline__ unsigned cvt_pk_bf16(float a, float b) {
    unsigned d;
    asm("v_cvt_pk_bf16_f32 %0, %1, %2" : "=v"(d) : "v"(a), "v"(b));
    return d;
}
__device__ __forceinline__ float frcp(float v) {          // raw v_rcp_f32
    return __builtin_amdgcn_rcpf(v);
}
__device__ __forceinline__ float fsigmoid(float v) {
    return frcp(1.0f + __expf(-v));
}
__device__ __forceinline__ float ftanh(float v) {
    float e = __expf(2.0f * v);
    return fmaf(-2.0f, frcp(e + 1.0f), 1.0f);
}

// prep: w_hh -> wB bf16; w_ih -> wI bf16 [768][32] with k=28/29 = bias hi/lo
// (R,Z rows carry b_ih+b_hh; N rows carry b_ih only — b_hh_n stays separate).
__global__ void prep_w(const float* __restrict__ w_hh, const float* __restrict__ w_ih,
                       const float* __restrict__ b_ih, const float* __restrict__ b_hh,
                       short* __restrict__ wB, short* __restrict__ wI) {
    int idx = blockIdx.x * 256 + threadIdx.x;
    if (idx < G3 * N_MID) wB[idx] = f2bf(w_hh[idx]);
    if (idx < G3 * 32) {
        int g = idx >> 5, k = idx & 31;
        float v = 0.0f;
        if (k < N_IN) {
            v = w_ih[g * N_IN + k];
        } else if (k == 28 || k == 29) {
            float bias = (g < 2 * N_MID) ? (b_ih[g] + b_hh[g]) : b_ih[g];
            v = (k == 28) ? bias : (bias - bf2f(f2bf(bias)));
        }
        wI[idx] = f2bf(v);
    }
}

// One timestep. RB = read buffer, writes RB^1. HID=false: t=0 (h=0).
// xA/xB hold x(t) (prefetched last step); this step prefetches x(t+1).
// Each wave: 16 cols x 3 gates, ALL weights register-resident; LDS = h only.
template<bool HID, int RB, bool LAST>
__device__ __forceinline__ void gru_step(
    int t, const float* __restrict__ x, int rowbase,
    int l15, int lg, int c,
    short (&hl)[2][32][17][8],
    const bf16x8 (&wreg)[3][8],
    const bf16x8 (&wireg)[3],
    float bHN,
    float (&hold)[4],
    float4 &xA, float4 &xB)
{
    constexpr int WB = RB ^ 1;

    // ---- prefetch x(t+1); consumed NEXT step (latency hidden by full step)
    float4 nA, nB;
    if (!LAST) {
        const float* xp =
            x + (size_t)(rowbase + l15) * (SEQ * N_IN) + (t + 1) * N_IN + lg * 8;
        nA = *(const float4*)xp;
        nB.x = 0.f; nB.y = 0.f; nB.z = 0.f; nB.w = 0.f;
        if (lg < 3) nB = *(const float4*)(xp + 4);
    }

    const f32x4 zero4 = splat4(0.0f);
    f32x4 aR, aZ, aIN, aHN;

    if constexpr (HID) {
        // depth-2 ping-pong on the h A-fragments; B always register-resident
        bf16x8 ah2[2];
        ah2[0] = *(const bf16x8*)&hl[RB][lg][l15][0];
        __builtin_amdgcn_s_setprio(1);
        #pragma unroll
        for (int ks = 0; ks < 8; ++ks) {
            const int cur = ks & 1, nxt = cur ^ 1;
            if (ks < 7)
                ah2[nxt] = *(const bf16x8*)&hl[RB][(ks + 1) * 4 + lg][l15][0];
            if (ks == 0) {   // C-operand supplies init: no acc-init movs
                aR  = MFMA(ah2[cur], wreg[0][0], zero4);
                aZ  = MFMA(ah2[cur], wreg[1][0], zero4);
                aHN = MFMA(ah2[cur], wreg[2][0], splat4(bHN));
            } else {
                aR  = MFMA(ah2[cur], wreg[0][ks], aR);
                aZ  = MFMA(ah2[cur], wreg[1][ks], aZ);
                aHN = MFMA(ah2[cur], wreg[2][ks], aHN);
            }
        }
        __builtin_amdgcn_s_setprio(0);
    }

    // ---- x(t) trunc hi/lo split + input projection (+ bias via k=28/29)
    float xv[8] = {xA.x, xA.y, xA.z, xA.w, xB.x, xB.y, xB.z, xB.w};
    bf16x8 xh, xlo;
    #pragma unroll
    for (int e = 0; e < 8; ++e) {
        unsigned int u = __float_as_uint(xv[e]);
        xh[e] = (short)(u >> 16);
        float rem = xv[e] - __uint_as_float(u & 0xffff0000u);
        xlo[e] = (short)(__float_as_uint(rem) >> 16);
    }
    if (lg == 3) {               // bias-carrier lanes: k=28,29 multiply by 1.0
        xh[4] = (short)0x3F80;
        xh[5] = (short)0x3F80;   // xlo[4],xlo[5] already 0 (xv==0 there)
    }
    if constexpr (HID) {
        aR  = MFMA(xh, wireg[0], aR);
        aZ  = MFMA(xh, wireg[1], aZ);
        aIN = MFMA(xh, wireg[2], zero4);
    } else {
        aR  = MFMA(xh, wireg[0], zero4);
        aZ  = MFMA(xh, wireg[1], zero4);
        aIN = MFMA(xh, wireg[2], zero4);
        aHN = splat4(bHN);
    }
    aIN = MFMA(xlo, wireg[2], aIN);

    // ---- lane-local GRU update (4 values); write h(t+1) A-fragments
    float hn4[4];
    #pragma unroll
    for (int j = 0; j < 4; ++j) {
        float r = fsigmoid(aR[j]);
        float z = fsigmoid(aZ[j]);
        float n = ftanh(aIN[j] + r * aHN[j]);
        float hnew = fmaf(z, hold[j] - n, n);
        hold[j] = hnew;
        hn4[j] = hnew;
    }
    unsigned p01 = cvt_pk_bf16(hn4[0], hn4[1]);
    unsigned p23 = cvt_pk_bf16(hn4[2], hn4[3]);
    short* bp = &hl[WB][c >> 3][4 * lg][c & 7];   // row stride = 8 shorts
    bp[0]  = (short)(p01 & 0xffffu);
    bp[8]  = (short)(p01 >> 16);
    bp[16] = (short)(p23 & 0xffffu);
    bp[24] = (short)(p23 >> 16);

    if (!LAST) { xA = nA; xB = nB; }   // rotate prefetch
    __syncthreads();
}

__global__ __launch_bounds__(THREADS, 1) void gru_onecu(
    const float* __restrict__ x,     // [B][T][28]
    const short* __restrict__ wB,    // [768][256] bf16
    const short* __restrict__ wI,    // [768][32] bf16 (k28/29 = bias hi/lo)
    const float* __restrict__ b_hh,
    const float* __restrict__ fc_w,  // [28][256]
    const float* __restrict__ fc_b,
    float* __restrict__ out)         // [B][28]
{
    // h double-buffer A-fragments, single bf16: [buf][kchunk][row(pad17)][pos] (17 KB)
    __shared__ short hl[2][32][17][8];
    __shared__ float hfc[ROWS][257];        // 16.4 KB FC scratch (33.8 KB total)

    const int tid  = threadIdx.x;
    const int lane = tid & 63;
    const int l15  = lane & 15;
    const int lg   = lane >> 4;
    const int wv   = tid >> 6;              // 0..15: wave owns cols [16wv,16wv+16)
    const int rowbase = blockIdx.x * ROWS;
    const int c = wv * 16 + l15;            // this lane's hidden column

    // ---- one-time: ALL 8 K-slices (3 gates x 16 cols) + w_ih into registers
    bf16x8 wreg[3][8];
    bf16x8 wireg[3];
    const float bHN = b_hh[512 + c];
    #pragma unroll
    for (int g = 0; g < 3; ++g) {
        wireg[g] = *(const bf16x8*)(wI + ((size_t)(g * 256 + c)) * 32 + lg * 8);
        #pragma unroll
        for (int ks = 0; ks < 8; ++ks)
            wreg[g][ks] =
                *(const bf16x8*)(wB + ((size_t)(g * 256 + c)) * 256 + ks * 32 + lg * 8);
    }

    float hold[4] = {};

    // ---- prologue x(0) load
    float4 xA, xB;
    {
        const float* xp = x + (size_t)(rowbase + l15) * (SEQ * N_IN) + lg * 8;
        xA = *(const float4*)xp;
        xB.x = 0.f; xB.y = 0.f; xB.z = 0.f; xB.w = 0.f;
        if (lg < 3) xB = *(const float4*)(xp + 4);
    }

    // t=0 (h=0) writes buf1; pairs keep compile-time buffer indices
    gru_step<false, 0, false>(0, x, rowbase, l15, lg, c, hl, wreg,
                              wireg, bHN, hold, xA, xB);
    for (int tt = 1; tt < SEQ - 1; tt += 2) {
        gru_step<true, 1, false>(tt, x, rowbase, l15, lg, c, hl, wreg,
                                 wireg, bHN, hold, xA, xB);
        gru_step<true, 0, false>(tt + 1, x, rowbase, l15, lg, c, hl, wreg,
                                 wireg, bHN, hold, xA, xB);
    }
    gru_step<true, 1, true>(SEQ - 1, x, rowbase, l15, lg, c, hl, wreg,
                            wireg, bHN, hold, xA, xB);

    // ---- FC epilogue: h(SEQ) in buf0
    {
        int r = tid >> 6, kg = tid & 63;    // each thread converts 4 k's
        #pragma unroll
        for (int e = 0; e < 4; ++e) {
            int k = kg * 4 + e;
            hfc[r][k] = bf2f(hl[0][k >> 3][r][k & 7]);
        }
    }
    __syncthreads();
    if (tid < ROWS * N_OUT) {
        int r = tid / N_OUT, o = tid - r * N_OUT;
        float acc = fc_b[o];
        #pragma unroll
        for (int k4 = 0; k4 < 64; ++k4) {
            float4 hv = *(const float4*)&hfc[r][k4 * 4];
            float4 wv4 = *(const float4*)&fc_w[o * 256 + k4 * 4];
            acc = fmaf(hv.x, wv4.x, acc);
            acc = fmaf(hv.y, wv4.y, acc);
            acc = fmaf(hv.z, wv4.z, acc);
            acc = fmaf(hv.w, wv4.w, acc);
        }
        out[(size_t)(rowbase + r) * N_OUT + o] = acc;
    }
}

extern "C" void kernel_launch(void* const* d_in, const int* in_sizes, int n_in,
                              void* d_out, int out_size, void* d_ws, size_t ws_size,
                              hipStream_t stream) {
    const float* x    = (const float*)d_in[0];
    const float* w_ih = (const float*)d_in[1];
    const float* w_hh = (const float*)d_in[2];
    const float* b_ih = (const float*)d_in[3];
    const float* b_hh = (const float*)d_in[4];
    const float* fc_w = (const float*)d_in[5];
    const float* fc_b = (const float*)d_in[6];
    float* out = (float*)d_out;

    short* wB = (short*)d_ws;                 // [768][256] bf16 = 384 KB
    short* wI = wB + G3 * N_MID;              // [768][32]  bf16 =  48 KB

    hipLaunchKernelGGL(prep_w, dim3(768), dim3(256), 0, stream,
                       w_hh, w_ih, b_ih, b_hh, wB, wI);
    hipLaunchKernelGGL(gru_onecu, dim3(NBLK), dim3(THREADS), 0, stream,
                       x, wB, wI, b_hh, fc_w, fc_b, out);
}

// Round 14
// 85.311 us; speedup vs baseline: 1.8451x; 1.8451x over previous
//
#include <hip/hip_runtime.h>
#include <hip/hip_bf16.h>
#include <math.h>

#define N_IN 28
#define N_MID 256
#define N_OUT 28
#define SEQ 28
#define BATCH 4096
#define G3 768
#define ROWS 16
#define THREADS 512
#define NBLK (BATCH / ROWS)   // 256

typedef __attribute__((ext_vector_type(8))) short bf16x8;
typedef __attribute__((ext_vector_type(4))) float f32x4;

#define MFMA(a, b, c) __builtin_amdgcn_mfma_f32_16x16x32_bf16((a), (b), (c), 0, 0, 0)

__device__ __forceinline__ f32x4 splat4(float v) {
    f32x4 r;
    r[0] = v; r[1] = v; r[2] = v; r[3] = v;
    return r;
}

__device__ __forceinline__ short f2bf(float v) {          // RNE (prep kernel)
    __hip_bfloat16 b = __float2bfloat16(v);
    return *reinterpret_cast<short*>(&b);
}
__device__ __forceinline__ float bf2f(short s) {
    unsigned int u = ((unsigned int)(unsigned short)s) << 16;
    return __uint_as_float(u);
}
// HW packed f32->bf16 RNE: lo16 = bf16(a), hi16 = bf16(b)
__device__ __forceinline__ unsigned cvt_pk_bf16(float a, float b) {
    unsigned d;
    asm("v_cvt_pk_bf16_f32 %0, %1, %2" : "=v"(d) : "v"(a), "v"(b));
    return d;
}
__device__ __forceinline__ float frcp(float v) {          // raw v_rcp_f32
    return __builtin_amdgcn_rcpf(v);
}
__device__ __forceinline__ float fsigmoid(float v) {
    return frcp(1.0f + __expf(-v));
}
__device__ __forceinline__ float ftanh(float v) {
    float e = __expf(2.0f * v);
    return fmaf(-2.0f, frcp(e + 1.0f), 1.0f);
}

// prep: w_hh -> wB bf16; w_ih -> wI bf16 [768][32] with k=28/29 = bias hi/lo
// (R,Z rows carry b_ih+b_hh; N rows carry b_ih only — b_hh_n stays separate).
__global__ void prep_w(const float* __restrict__ w_hh, const float* __restrict__ w_ih,
                       const float* __restrict__ b_ih, const float* __restrict__ b_hh,
                       short* __restrict__ wB, short* __restrict__ wI) {
    int idx = blockIdx.x * 256 + threadIdx.x;
    if (idx < G3 * N_MID) wB[idx] = f2bf(w_hh[idx]);
    if (idx < G3 * 32) {
        int g = idx >> 5, k = idx & 31;
        float v = 0.0f;
        if (k < N_IN) {
            v = w_ih[g * N_IN + k];
        } else if (k == 28 || k == 29) {
            float bias = (g < 2 * N_MID) ? (b_ih[g] + b_hh[g]) : b_ih[g];
            v = (k == 28) ? bias : (bias - bf2f(f2bf(bias)));
        }
        wI[idx] = f2bf(v);
    }
}

// One timestep. RB = read buffer, writes RB^1. HID=false: t=0 (h=0).
// xA/xB hold x(t) (prefetched last step); this step prefetches x(t+1).
// K-slices 0..6 register-resident; slice 7 from LDS, read LAST (after the
// ah-read burst drains the LDS pipe).
template<bool HID, int RB, bool LAST>
__device__ __forceinline__ void gru_step(
    int t, const float* __restrict__ x, int rowbase,
    int l15, int lg, int wv, int lane,
    short (&hl)[2][32][17][8],
    const short (&wlds)[3][16][64][8],
    const bf16x8 (&wreg)[3][2][7],
    const bf16x8 (&wireg)[3][2],
    const float (&bHN)[2],
    float (&hold)[2][4], const int (&colA)[2],
    float4 &xA, float4 &xB)
{
    constexpr int WB = RB ^ 1;

    // ---- prefetch x(t+1); consumed NEXT step (latency hidden by full step)
    float4 nA, nB;
    if (!LAST) {
        const float* xp =
            x + (size_t)(rowbase + l15) * (SEQ * N_IN) + (t + 1) * N_IN + lg * 8;
        nA = *(const float4*)xp;
        nB.x = 0.f; nB.y = 0.f; nB.z = 0.f; nB.w = 0.f;
        if (lg < 3) nB = *(const float4*)(xp + 4);
    }

    const f32x4 zero4 = splat4(0.0f);
    f32x4 aR[2], aZ[2], aIN[2], aHN[2];

    if constexpr (HID) {
        // depth-2 ping-pong on h A-fragments; reg-B ksteps 0..6 first,
        // the single LDS-B kstep (7) last.
        bf16x8 ah2[2];
        ah2[0] = *(const bf16x8*)&hl[RB][lg][l15][0];
        __builtin_amdgcn_s_setprio(1);
        #pragma unroll
        for (int ks = 0; ks < 8; ++ks) {
            const int cur = ks & 1, nxt = cur ^ 1;
            if (ks < 7)
                ah2[nxt] = *(const bf16x8*)&hl[RB][(ks + 1) * 4 + lg][l15][0];
            #pragma unroll
            for (int a = 0; a < 2; ++a) {
                bf16x8 b0, b1, b2;
                if (ks < 7) {
                    b0 = wreg[0][a][ks]; b1 = wreg[1][a][ks]; b2 = wreg[2][a][ks];
                } else {
                    const int cg = 2 * wv + a;
                    b0 = *(const bf16x8*)&wlds[0][cg][lane][0];
                    b1 = *(const bf16x8*)&wlds[1][cg][lane][0];
                    b2 = *(const bf16x8*)&wlds[2][cg][lane][0];
                }
                if (ks == 0) {   // C-operand supplies init: no acc-init movs
                    f32x4 cHN = splat4(bHN[a]);
                    aR[a]  = MFMA(ah2[cur], b0, zero4);
                    aZ[a]  = MFMA(ah2[cur], b1, zero4);
                    aHN[a] = MFMA(ah2[cur], b2, cHN);
                } else {
                    aR[a]  = MFMA(ah2[cur], b0, aR[a]);
                    aZ[a]  = MFMA(ah2[cur], b1, aZ[a]);
                    aHN[a] = MFMA(ah2[cur], b2, aHN[a]);
                }
            }
        }
        __builtin_amdgcn_s_setprio(0);
    }

    // ---- x(t) trunc hi/lo split + input projection (+ bias via k=28/29)
    float xv[8] = {xA.x, xA.y, xA.z, xA.w, xB.x, xB.y, xB.z, xB.w};
    bf16x8 xh, xlo;
    #pragma unroll
    for (int e = 0; e < 8; ++e) {
        unsigned int u = __float_as_uint(xv[e]);
        xh[e] = (short)(u >> 16);
        float rem = xv[e] - __uint_as_float(u & 0xffff0000u);
        xlo[e] = (short)(__float_as_uint(rem) >> 16);
    }
    if (lg == 3) {               // bias-carrier lanes: k=28,29 multiply by 1.0
        xh[4] = (short)0x3F80;
        xh[5] = (short)0x3F80;   // xlo[4],xlo[5] already 0 (xv==0 there)
    }
    #pragma unroll
    for (int a = 0; a < 2; ++a) {
        if constexpr (HID) {
            aR[a]  = MFMA(xh, wireg[0][a], aR[a]);
            aZ[a]  = MFMA(xh, wireg[1][a], aZ[a]);
            aIN[a] = MFMA(xh, wireg[2][a], zero4);
        } else {
            aR[a]  = MFMA(xh, wireg[0][a], zero4);
            aZ[a]  = MFMA(xh, wireg[1][a], zero4);
            aIN[a] = MFMA(xh, wireg[2][a], zero4);
            aHN[a] = splat4(bHN[a]);
        }
        aIN[a] = MFMA(xlo, wireg[2][a], aIN[a]);
    }

    // ---- lane-local GRU update; write h(t+1) A-fragments (packed HW converts)
    #pragma unroll
    for (int a = 0; a < 2; ++a) {
        const int c = colA[a];
        float hn4[4];
        #pragma unroll
        for (int j = 0; j < 4; ++j) {
            float r = fsigmoid(aR[a][j]);
            float z = fsigmoid(aZ[a][j]);
            float n = ftanh(aIN[a][j] + r * aHN[a][j]);
            float hnew = fmaf(z, hold[a][j] - n, n);
            hold[a][j] = hnew;
            hn4[j] = hnew;
        }
        unsigned p01 = cvt_pk_bf16(hn4[0], hn4[1]);
        unsigned p23 = cvt_pk_bf16(hn4[2], hn4[3]);
        short* bp = &hl[WB][c >> 3][4 * lg][c & 7];   // row stride = 8 shorts
        bp[0]  = (short)(p01 & 0xffffu);
        bp[8]  = (short)(p01 >> 16);
        bp[16] = (short)(p23 & 0xffffu);
        bp[24] = (short)(p23 >> 16);
    }

    if (!LAST) { xA = nA; xB = nB; }   // rotate prefetch
    __syncthreads();
}

__global__ __launch_bounds__(THREADS, 2) void gru_onecu(
    const float* __restrict__ x,     // [B][T][28]
    const short* __restrict__ wB,    // [768][256] bf16
    const short* __restrict__ wI,    // [768][32] bf16 (k28/29 = bias hi/lo)
    const float* __restrict__ b_hh,
    const float* __restrict__ fc_w,  // [28][256]
    const float* __restrict__ fc_b,
    float* __restrict__ out)         // [B][28]
{
    // Weight K-slice 7 as frag-linear B-fragments (48 KB)
    __shared__ short wlds[3][16][64][8];
    // h double-buffer A-fragments, single bf16 (17 KB)
    __shared__ short hl[2][32][17][8];
    __shared__ float hfc[ROWS][257];        // 16.4 KB FC scratch (81.4 KB total)

    const int tid  = threadIdx.x;
    const int lane = tid & 63;
    const int l15  = lane & 15;
    const int lg   = lane >> 4;
    const int wv   = tid >> 6;              // wave owns cols [32wv, 32wv+32)
    const int rowbase = blockIdx.x * ROWS;

    // ---- one-time: stage K-slice 7 into LDS (frag-linear, conflict-free)
    for (int idx = tid; idx < 3 * 16 * 64; idx += THREADS) {
        int L    = idx & 63;
        int frag = idx >> 6;              // 0..47
        int g    = frag >> 4;
        int cg   = frag & 15;
        int col  = cg * 16 + (L & 15);
        int k0   = 7 * 32 + (L >> 4) * 8;
        *(bf16x8*)&wlds[g][cg][L][0] =
            *(const bf16x8*)(wB + ((size_t)(g * 256 + col)) * 256 + k0);
    }

    // ---- one-time: K-slices 0..6 + w_ih into registers, bHN scalars
    bf16x8 wreg[3][2][7];
    bf16x8 wireg[3][2];
    int   colA[2];
    float bHN[2];
    #pragma unroll
    for (int a = 0; a < 2; ++a) {
        const int c = wv * 32 + a * 16 + l15;
        colA[a] = c;
        bHN[a]  = b_hh[512 + c];
        #pragma unroll
        for (int g = 0; g < 3; ++g) {
            wireg[g][a] = *(const bf16x8*)(wI + ((size_t)(g * 256 + c)) * 32 + lg * 8);
            #pragma unroll
            for (int ks = 0; ks < 7; ++ks)
                wreg[g][a][ks] =
                    *(const bf16x8*)(wB + ((size_t)(g * 256 + c)) * 256 + ks * 32 + lg * 8);
        }
    }

    float hold[2][4] = {};

    // ---- prologue x(0) load
    float4 xA, xB;
    {
        const float* xp = x + (size_t)(rowbase + l15) * (SEQ * N_IN) + lg * 8;
        xA = *(const float4*)xp;
        xB.x = 0.f; xB.y = 0.f; xB.z = 0.f; xB.w = 0.f;
        if (lg < 3) xB = *(const float4*)(xp + 4);
    }

    __syncthreads();

    // t=0 (h=0) writes buf1; pairs keep compile-time buffer indices
    gru_step<false, 0, false>(0, x, rowbase, l15, lg, wv, lane, hl, wlds, wreg,
                              wireg, bHN, hold, colA, xA, xB);
    for (int tt = 1; tt < SEQ - 1; tt += 2) {
        gru_step<true, 1, false>(tt, x, rowbase, l15, lg, wv, lane, hl, wlds, wreg,
                                 wireg, bHN, hold, colA, xA, xB);
        gru_step<true, 0, false>(tt + 1, x, rowbase, l15, lg, wv, lane, hl, wlds, wreg,
                                 wireg, bHN, hold, colA, xA, xB);
    }
    gru_step<true, 1, true>(SEQ - 1, x, rowbase, l15, lg, wv, lane, hl, wlds, wreg,
                            wireg, bHN, hold, colA, xA, xB);

    // ---- FC epilogue: h(SEQ) in buf0
    {
        int r = tid >> 5, kg = tid & 31;
        #pragma unroll
        for (int e = 0; e < 8; ++e) {
            int k = kg * 8 + e;
            hfc[r][k] = bf2f(hl[0][k >> 3][r][k & 7]);
        }
    }
    __syncthreads();
    if (tid < ROWS * N_OUT) {
        int r = tid / N_OUT, o = tid - r * N_OUT;
        float acc = fc_b[o];
        #pragma unroll
        for (int k4 = 0; k4 < 64; ++k4) {
            float4 hv = *(const float4*)&hfc[r][k4 * 4];
            float4 wv4 = *(const float4*)&fc_w[o * 256 + k4 * 4];
            acc = fmaf(hv.x, wv4.x, acc);
            acc = fmaf(hv.y, wv4.y, acc);
            acc = fmaf(hv.z, wv4.z, acc);
            acc = fmaf(hv.w, wv4.w, acc);
        }
        out[(size_t)(rowbase + r) * N_OUT + o] = acc;
    }
}

extern "C" void kernel_launch(void* const* d_in, const int* in_sizes, int n_in,
                              void* d_out, int out_size, void* d_ws, size_t ws_size,
                              hipStream_t stream) {
    const float* x    = (const float*)d_in[0];
    const float* w_ih = (const float*)d_in[1];
    const float* w_hh = (const float*)d_in[2];
    const float* b_ih = (const float*)d_in[3];
    const float* b_hh = (const float*)d_in[4];
    const float* fc_w = (const float*)d_in[5];
    const float* fc_b = (const float*)d_in[6];
    float* out = (float*)d_out;

    short* wB = (short*)d_ws;                 // [768][256] bf16 = 384 KB
    short* wI = wB + G3 * N_MID;              // [768][32]  bf16 =  48 KB

    hipLaunchKernelGGL(prep_w, dim3(768), dim3(256), 0, stream,
                       w_hh, w_ih, b_ih, b_hh, wB, wI);
    hipLaunchKernelGGL(gru_onecu, dim3(NBLK), dim3(THREADS), 0, stream,
                       x, wB, wI, b_hh, fc_w, fc_b, out);
}

// Round 15
// 77.162 us; speedup vs baseline: 2.0400x; 1.1056x over previous
//
#include <hip/hip_runtime.h>
#include <hip/hip_bf16.h>
#include <math.h>

#define N_IN 28
#define N_MID 256
#define N_OUT 28
#define SEQ 28
#define BATCH 4096
#define G3 768
#define ROWS 16
#define THREADS 512
#define NBLK (BATCH / ROWS)   // 256

#define LOG2E  1.44269504f
#define LOG2E2 2.88539008f

typedef __attribute__((ext_vector_type(8))) short bf16x8;
typedef __attribute__((ext_vector_type(4))) float f32x4;

#define MFMA(a, b, c) __builtin_amdgcn_mfma_f32_16x16x32_bf16((a), (b), (c), 0, 0, 0)

__device__ __forceinline__ f32x4 splat4(float v) {
    f32x4 r;
    r[0] = v; r[1] = v; r[2] = v; r[3] = v;
    return r;
}

__device__ __forceinline__ short f2bf(float v) {          // RNE (prep kernel)
    __hip_bfloat16 b = __float2bfloat16(v);
    return *reinterpret_cast<short*>(&b);
}
__device__ __forceinline__ float bf2f(short s) {
    unsigned int u = ((unsigned int)(unsigned short)s) << 16;
    return __uint_as_float(u);
}
// HW packed f32->bf16 RNE: lo16 = bf16(a), hi16 = bf16(b)
__device__ __forceinline__ unsigned cvt_pk_bf16(float a, float b) {
    unsigned d;
    asm("v_cvt_pk_bf16_f32 %0, %1, %2" : "=v"(d) : "v"(a), "v"(b));
    return d;
}
__device__ __forceinline__ float frcp(float v) {          // raw v_rcp_f32
    return __builtin_amdgcn_rcpf(v);
}
__device__ __forceinline__ float fexp2(float v) {         // raw v_exp_f32 (2^x)
#if __has_builtin(__builtin_amdgcn_exp2f)
    return __builtin_amdgcn_exp2f(v);
#else
    return __expf(v * 0.69314718f);
#endif
}
// pre-activations arrive pre-scaled by log2e (R,Z) / 2*log2e (N) via weights
__device__ __forceinline__ float fsigmoid2(float v) {     // v = log2e * act
    return frcp(1.0f + fexp2(-v));
}
__device__ __forceinline__ float ftanh2(float v) {        // v = 2*log2e * act
    return fmaf(-2.0f, frcp(1.0f + fexp2(v)), 1.0f);
}

// prep: w_hh -> wB bf16 (rows prescaled: R/Z x log2e, N x 2log2e);
// w_ih -> wI bf16 [768][32], same prescale, k=28/29 = scaled bias hi/lo.
__global__ void prep_w(const float* __restrict__ w_hh, const float* __restrict__ w_ih,
                       const float* __restrict__ b_ih, const float* __restrict__ b_hh,
                       short* __restrict__ wB, short* __restrict__ wI) {
    int idx = blockIdx.x * 256 + threadIdx.x;
    if (idx < G3 * N_MID) {
        int g = idx >> 8;
        float s = (g < 2 * N_MID) ? LOG2E : LOG2E2;
        wB[idx] = f2bf(w_hh[idx] * s);
    }
    if (idx < G3 * 32) {
        int g = idx >> 5, k = idx & 31;
        float s = (g < 2 * N_MID) ? LOG2E : LOG2E2;
        float v = 0.0f;
        if (k < N_IN) {
            v = w_ih[g * N_IN + k] * s;
        } else if (k == 28 || k == 29) {
            float bias = ((g < 2 * N_MID) ? (b_ih[g] + b_hh[g]) : b_ih[g]) * s;
            v = (k == 28) ? bias : (bias - bf2f(f2bf(bias)));
        }
        wI[idx] = f2bf(v);
    }
}

// One timestep. RB = read buffer, writes RB^1. HID=false: t=0 (h=0).
// xA/xB hold x(t) (prefetched last step); this step prefetches x(t+1).
// x is hi-only bf16 (RNE via cvt_pk); bias rides k=28/29 carriers (lg==3).
// K-slices 0..5 register-resident, slices 6,7 from LDS (read first: ord).
template<bool HID, int RB, bool LAST>
__device__ __forceinline__ void gru_step(
    int t, const float* __restrict__ x, int rowbase,
    int l15, int lg, int wv, int lane,
    short (&hl)[2][32][17][8],
    const short (&wlds)[2][3][16][64][8],
    const bf16x8 (&wreg)[3][2][6],
    const bf16x8 (&wireg)[3][2],
    const float (&bHN)[2],
    float (&hold)[2][4], const int (&colA)[2],
    float4 &xA, float4 &xB)
{
    constexpr int WB = RB ^ 1;

    // ---- prefetch x(t+1); consumed NEXT step (latency hidden by full step)
    float4 nA, nB;
    if (!LAST) {
        const float* xp =
            x + (size_t)(rowbase + l15) * (SEQ * N_IN) + (t + 1) * N_IN + lg * 8;
        nA = *(const float4*)xp;
        nB.x = 0.f; nB.y = 0.f; nB.z = 0.f; nB.w = 0.f;
        if (lg < 3) nB = *(const float4*)(xp + 4);
    }

    const f32x4 zero4 = splat4(0.0f);
    f32x4 aR[2], aZ[2], aIN[2], aHN[2];

    if constexpr (HID) {
        // K-slice order {6,7,0..5}: LDS-B slices first so their reads pipeline
        // with the ah chain; reg-B slices consume during drain.
        constexpr int ord[8] = {6, 7, 0, 1, 2, 3, 4, 5};
        bf16x8 ah2[2];
        ah2[0] = *(const bf16x8*)&hl[RB][ord[0] * 4 + lg][l15][0];
        __builtin_amdgcn_s_setprio(1);
        #pragma unroll
        for (int i = 0; i < 8; ++i) {
            const int ks = ord[i];
            const int cur = i & 1, nxt = cur ^ 1;
            if (i < 7)
                ah2[nxt] = *(const bf16x8*)&hl[RB][ord[i + 1] * 4 + lg][l15][0];
            #pragma unroll
            for (int a = 0; a < 2; ++a) {
                bf16x8 b0, b1, b2;
                if (ks < 6) {
                    b0 = wreg[0][a][ks]; b1 = wreg[1][a][ks]; b2 = wreg[2][a][ks];
                } else {
                    const int cg = 2 * wv + a;
                    b0 = *(const bf16x8*)&wlds[ks - 6][0][cg][lane][0];
                    b1 = *(const bf16x8*)&wlds[ks - 6][1][cg][lane][0];
                    b2 = *(const bf16x8*)&wlds[ks - 6][2][cg][lane][0];
                }
                if (i == 0) {   // C-operand supplies init: no acc-init movs
                    f32x4 cHN = splat4(bHN[a]);
                    aR[a]  = MFMA(ah2[cur], b0, zero4);
                    aZ[a]  = MFMA(ah2[cur], b1, zero4);
                    aHN[a] = MFMA(ah2[cur], b2, cHN);
                } else {
                    aR[a]  = MFMA(ah2[cur], b0, aR[a]);
                    aZ[a]  = MFMA(ah2[cur], b1, aZ[a]);
                    aHN[a] = MFMA(ah2[cur], b2, aHN[a]);
                }
            }
        }
        __builtin_amdgcn_s_setprio(0);
    }

    // ---- x(t) hi-only bf16 via packed HW converts + input projection
    float xv[8] = {xA.x, xA.y, xA.z, xA.w, xB.x, xB.y, xB.z, xB.w};
    unsigned w0 = cvt_pk_bf16(xv[0], xv[1]);
    unsigned w1 = cvt_pk_bf16(xv[2], xv[3]);
    unsigned w2 = cvt_pk_bf16(xv[4], xv[5]);
    unsigned w3 = cvt_pk_bf16(xv[6], xv[7]);
    if (lg == 3) w2 = 0x3F803F80u;   // bias carriers k=28,29 multiply by 1.0
    bf16x8 xh;
    {
        unsigned* xu = (unsigned*)&xh;
        xu[0] = w0; xu[1] = w1; xu[2] = w2; xu[3] = w3;
    }
    #pragma unroll
    for (int a = 0; a < 2; ++a) {
        if constexpr (HID) {
            aR[a]  = MFMA(xh, wireg[0][a], aR[a]);
            aZ[a]  = MFMA(xh, wireg[1][a], aZ[a]);
            aIN[a] = MFMA(xh, wireg[2][a], zero4);
        } else {
            aR[a]  = MFMA(xh, wireg[0][a], zero4);
            aZ[a]  = MFMA(xh, wireg[1][a], zero4);
            aIN[a] = MFMA(xh, wireg[2][a], zero4);
            aHN[a] = splat4(bHN[a]);
        }
    }

    // ---- lane-local GRU update; write h(t+1) A-fragments (packed HW converts)
    #pragma unroll
    for (int a = 0; a < 2; ++a) {
        const int c = colA[a];
        float hn4[4];
        #pragma unroll
        for (int j = 0; j < 4; ++j) {
            float r = fsigmoid2(aR[a][j]);
            float z = fsigmoid2(aZ[a][j]);
            float n = ftanh2(aIN[a][j] + r * aHN[a][j]);
            float hnew = fmaf(z, hold[a][j] - n, n);
            hold[a][j] = hnew;
            hn4[j] = hnew;
        }
        unsigned p01 = cvt_pk_bf16(hn4[0], hn4[1]);
        unsigned p23 = cvt_pk_bf16(hn4[2], hn4[3]);
        short* bp = &hl[WB][c >> 3][4 * lg][c & 7];   // row stride = 8 shorts
        bp[0]  = (short)(p01 & 0xffffu);
        bp[8]  = (short)(p01 >> 16);
        bp[16] = (short)(p23 & 0xffffu);
        bp[24] = (short)(p23 >> 16);
    }

    if (!LAST) { xA = nA; xB = nB; }   // rotate prefetch
    __syncthreads();
}

__global__ __launch_bounds__(THREADS, 2) void gru_onecu(
    const float* __restrict__ x,     // [B][T][28]
    const short* __restrict__ wB,    // [768][256] bf16 (log2e-prescaled)
    const short* __restrict__ wI,    // [768][32] bf16 (prescaled, k28/29 bias)
    const float* __restrict__ b_hh,
    const float* __restrict__ fc_w,  // [28][256]
    const float* __restrict__ fc_b,
    float* __restrict__ out)         // [B][28]
{
    // Weight K-slices 6,7 as frag-linear B-fragments (96 KB)
    __shared__ short wlds[2][3][16][64][8];
    // h double-buffer A-fragments, single bf16 (17 KB)
    __shared__ short hl[2][32][17][8];

    const int tid  = threadIdx.x;
    const int lane = tid & 63;
    const int l15  = lane & 15;
    const int lg   = lane >> 4;
    const int wv   = tid >> 6;              // wave owns cols [32wv, 32wv+32)
    const int rowbase = blockIdx.x * ROWS;

    // ---- one-time: stage K-slices 6,7 into LDS (frag-linear, conflict-free)
    for (int idx = tid; idx < 2 * 3 * 16 * 64; idx += THREADS) {
        int L    = idx & 63;
        int frag = idx >> 6;
        int ksl  = frag / 48;
        int rem  = frag - ksl * 48;
        int g    = rem >> 4;
        int cg   = rem & 15;
        int col  = cg * 16 + (L & 15);
        int k0   = (6 + ksl) * 32 + (L >> 4) * 8;
        *(bf16x8*)&wlds[ksl][g][cg][L][0] =
            *(const bf16x8*)(wB + ((size_t)(g * 256 + col)) * 256 + k0);
    }

    // ---- one-time: K-slices 0..5 + w_ih into registers, bHN scalars (scaled)
    bf16x8 wreg[3][2][6];
    bf16x8 wireg[3][2];
    int   colA[2];
    float bHN[2];
    #pragma unroll
    for (int a = 0; a < 2; ++a) {
        const int c = wv * 32 + a * 16 + l15;
        colA[a] = c;
        bHN[a]  = b_hh[512 + c] * LOG2E2;
        #pragma unroll
        for (int g = 0; g < 3; ++g) {
            wireg[g][a] = *(const bf16x8*)(wI + ((size_t)(g * 256 + c)) * 32 + lg * 8);
            #pragma unroll
            for (int ks = 0; ks < 6; ++ks)
                wreg[g][a][ks] =
                    *(const bf16x8*)(wB + ((size_t)(g * 256 + c)) * 256 + ks * 32 + lg * 8);
        }
    }

    float hold[2][4] = {};

    // ---- prologue x(0) load
    float4 xA, xB;
    {
        const float* xp = x + (size_t)(rowbase + l15) * (SEQ * N_IN) + lg * 8;
        xA = *(const float4*)xp;
        xB.x = 0.f; xB.y = 0.f; xB.z = 0.f; xB.w = 0.f;
        if (lg < 3) xB = *(const float4*)(xp + 4);
    }

    __syncthreads();

    // t=0 (h=0) writes buf1; pairs keep compile-time buffer indices
    gru_step<false, 0, false>(0, x, rowbase, l15, lg, wv, lane, hl, wlds, wreg,
                              wireg, bHN, hold, colA, xA, xB);
    for (int tt = 1; tt < SEQ - 1; tt += 2) {
        gru_step<true, 1, false>(tt, x, rowbase, l15, lg, wv, lane, hl, wlds, wreg,
                                 wireg, bHN, hold, colA, xA, xB);
        gru_step<true, 0, false>(tt + 1, x, rowbase, l15, lg, wv, lane, hl, wlds, wreg,
                                 wireg, bHN, hold, colA, xA, xB);
    }
    gru_step<true, 1, true>(SEQ - 1, x, rowbase, l15, lg, wv, lane, hl, wlds, wreg,
                            wireg, bHN, hold, colA, xA, xB);

    // ---- FC epilogue: h(SEQ) in buf0
    float* hf = (float*)&wlds[0][0][0][0][0];   // overlay 16 KB on weight LDS
    {
        int r = tid >> 5, kg = tid & 31;
        #pragma unroll
        for (int e = 0; e < 8; ++e) {
            int k = kg * 8 + e;
            hf[r * 256 + k] = bf2f(hl[0][k >> 3][r][k & 7]);
        }
    }
    __syncthreads();
    if (tid < ROWS * N_OUT) {
        int r = tid / N_OUT, o = tid - r * N_OUT;
        float acc = fc_b[o];
        #pragma unroll
        for (int k4 = 0; k4 < 64; ++k4) {
            float4 hv = *(const float4*)&hf[r * 256 + k4 * 4];
            float4 wv4 = *(const float4*)&fc_w[o * 256 + k4 * 4];
            acc = fmaf(hv.x, wv4.x, acc);
            acc = fmaf(hv.y, wv4.y, acc);
            acc = fmaf(hv.z, wv4.z, acc);
            acc = fmaf(hv.w, wv4.w, acc);
        }
        out[(size_t)(rowbase + r) * N_OUT + o] = acc;
    }
}

extern "C" void kernel_launch(void* const* d_in, const int* in_sizes, int n_in,
                              void* d_out, int out_size, void* d_ws, size_t ws_size,
                              hipStream_t stream) {
    const float* x    = (const float*)d_in[0];
    const float* w_ih = (const float*)d_in[1];
    const float* w_hh = (const float*)d_in[2];
    const float* b_ih = (const float*)d_in[3];
    const float* b_hh = (const float*)d_in[4];
    const float* fc_w = (const float*)d_in[5];
    const float* fc_b = (const float*)d_in[6];
    float* out = (float*)d_out;

    short* wB = (short*)d_ws;                 // [768][256] bf16 = 384 KB
    short* wI = wB + G3 * N_MID;              // [768][32]  bf16 =  48 KB

    hipLaunchKernelGGL(prep_w, dim3(768), dim3(256), 0, stream,
                       w_hh, w_ih, b_ih, b_hh, wB, wI);
    hipLaunchKernelGGL(gru_onecu, dim3(NBLK), dim3(THREADS), 0, stream,
                       x, wB, wI, b_hh, fc_w, fc_b, out);
}